// Round 12
// baseline (170.298 us; speedup 1.0000x reference)
//
#include <hip/hip_runtime.h>

#define N_NODES 100000
#define IN_F    256
#define OUT_F   256
#define BATCH   50000
#define NSAMP   25
#define K2      512
#define BKH     128     // K per staging half (fp32)
#define NTILE   1563    // ceil(100000/64)
#define XS      256     // persistent grid x

typedef _Float16 f16_t;
typedef f16_t f16x8 __attribute__((ext_vector_type(8)));
typedef float f32x4 __attribute__((ext_vector_type(4)));
typedef float f32x2 __attribute__((ext_vector_type(2)));
typedef __bf16 bf16_t;
typedef bf16_t bf16x8 __attribute__((ext_vector_type(8)));

#if defined(__has_builtin)
#if __has_builtin(__builtin_amdgcn_cvt_pk_f32_fp8) && __has_builtin(__builtin_amdgcn_cvt_pk_fp8_f32)
#define FP8_HW 1
#endif
#endif
#ifndef FP8_HW
#include <hip/hip_fp8.h>
#endif

// workspace layout (bytes): Pself f16 [100000][256], Pneigh fp8 [100000][256], Wg f16 [512][256]
#define P8_OFF   51200000L
#define WG_OFF   76800000L
#define WS_NEED  (WG_OFF + 512L * 256 * 2)

typedef __attribute__((address_space(1))) const unsigned int gas_uint;
typedef __attribute__((address_space(3))) unsigned int las_uint;

__device__ __forceinline__ void gll16(const void* g, void* l) {
    __builtin_amdgcn_global_load_lds((gas_uint*)g, (las_uint*)l, 16, 0, 0);
}

__device__ __forceinline__ float h2f(unsigned short u) {
    union { unsigned short u; f16_t h; } t; t.u = u; return (float)t.h;
}

__device__ __forceinline__ unsigned int pk_fp8x4(float a, float b, float c, float d) {
#ifdef FP8_HW
    unsigned int r = __builtin_amdgcn_cvt_pk_fp8_f32(a, b, 0u, false);
    r = __builtin_amdgcn_cvt_pk_fp8_f32(c, d, r, true);
    return r;
#else
    union { unsigned char b[4]; unsigned int u; } t;
    t.b[0] = __hip_fp8_e4m3(a).__x; t.b[1] = __hip_fp8_e4m3(b).__x;
    t.b[2] = __hip_fp8_e4m3(c).__x; t.b[3] = __hip_fp8_e4m3(d).__x;
    return t.u;
#endif
}

__device__ __forceinline__ void acc_fp8x4(unsigned int v, float4& a) {
#ifdef FP8_HW
    f32x2 lo = __builtin_amdgcn_cvt_pk_f32_fp8(v, false);
    f32x2 hi = __builtin_amdgcn_cvt_pk_f32_fp8(v, true);
    a.x += lo[0]; a.y += lo[1]; a.z += hi[0]; a.w += hi[1];
#else
    union { unsigned int u; unsigned char b[4]; } t; t.u = v;
    __hip_fp8_e4m3 e0, e1, e2, e3;
    e0.__x = t.b[0]; e1.__x = t.b[1]; e2.__x = t.b[2]; e3.__x = t.b[3];
    a.x += (float)e0; a.y += (float)e1; a.z += (float)e2; a.w += (float)e3;
#endif
}

// ---------------- Kernel 0: rearrange W -> Wg[512][256] f16 ----------------
__global__ void wconv(const float* __restrict__ W, f16_t* __restrict__ Wg) {
    int idx = blockIdx.x * 256 + threadIdx.x;
    int j = idx >> 8, k = idx & 255;
    float v = (j < 256) ? W[j * K2 + k] : W[(j - 256) * K2 + 256 + k];
    Wg[idx] = (f16_t)v;
}

// ---------------- Kernel 1: P = F @ Wg^T (f16 MFMA) ----------------
// grid (256, 2) persistent, 512-thread blocks (8 waves x 32 P-cols = 256 cols).
// amdgpu_waves_per_eu(4,4) pins EXACTLY 4 waves/EU: VGPR budget 128 >= our 88
// working set (no spill, unlike launch_bounds(512,4) which let the allocator
// target 8 waves/EU at 64 VGPR and spill wgall), giving 2 anti-phased
// blocks/CU to cover barrier/vmcnt stalls. k-loop has zero global-memory
// instructions (wgall in regs); counted vmcnt per FIFO analysis: steady h=0
// waits vmcnt(12) (8 epilogue stores + 4 fresh loads younger), h=1/first: 4.
__global__ __launch_bounds__(512)
__attribute__((amdgpu_waves_per_eu(4, 4)))
void proj_gemm(
    const float* __restrict__ features, const f16_t* __restrict__ Wg,
    f16_t* __restrict__ Pself, unsigned char* __restrict__ Pneigh8)
{
    __shared__ float buf[2][64 * BKH];   // 2 x 32 KB
    const int tid = threadIdx.x, lane = tid & 63, w = tid >> 6;   // w: 0..7
    const int q16 = lane >> 4, r16 = lane & 15;
    const int c0 = blockIdx.y * 256 + w * 32;     // this wave's global P-col base

    // ---- hoist the wave's whole Wg slice: 8 k-steps x 2 col-frags = 64 VGPR ----
    f16x8 wgall[8][2];
    #pragma unroll
    for (int s = 0; s < 8; ++s)
        #pragma unroll
        for (int ct = 0; ct < 2; ++ct)
            wgall[s][ct] = *(const f16x8*)&Wg[(long)(c0 + ct * 16 + r16) * 256 + s * 32 + q16 * 8];

    f32x4 acc[2][4];
    #pragma unroll
    for (int ct = 0; ct < 2; ++ct)
        #pragma unroll
        for (int rt = 0; rt < 4; ++rt) acc[ct][rt] = (f32x4){0.f, 0.f, 0.f, 0.f};

    // stage one 64x128 fp32 half-tile: 32 x 1KB chunks, 4 gll16 per wave.
    // LDS granule-swizzled via pre-swizzled GLOBAL source (rule 21):
    // phys granule p of row holds logical granule p ^ (row&7).
#define STAGE(TT, HH, BSEL)                                                     \
    {                                                                           \
        const long gr_ = (long)(TT) * 64;                                       \
        _Pragma("unroll")                                                       \
        for (int i_ = 0; i_ < 4; ++i_) {                                        \
            const int c_ = w * 4 + i_;                                          \
            const int row_ = 2 * c_ + (lane >> 5);                              \
            long srow_ = gr_ + row_; if (srow_ > N_NODES - 1) srow_ = N_NODES - 1; \
            const int sg4_ = ((lane & 31) ^ (row_ & 7)) * 4;                    \
            gll16(&features[srow_ * IN_F + (HH) * BKH + sg4_],                  \
                  &buf[BSEL][c_ * 256]);                                        \
        }                                                                       \
    }

    STAGE(blockIdx.x, 0, 0);
    int cur = 0;
    bool first = true;

    for (int t = blockIdx.x; t < NTILE; t += XS) {
        #pragma unroll
        for (int h = 0; h < 2; ++h) {
            __builtin_amdgcn_s_barrier();          // all waves done reading buf[cur^1]
            const int nt = (h == 0) ? t : t + XS;  // stage the NEXT half
            const bool hn = nt < NTILE;
            if (hn) {
                STAGE(nt, h ^ 1, cur ^ 1);
                if (h == 0 && !first) {
                    // FIFO: [h0-loads(4), stores(8), h1-loads(4)] -> need oldest 4
                    asm volatile("s_waitcnt vmcnt(12)" ::: "memory");
                } else {
                    asm volatile("s_waitcnt vmcnt(4)" ::: "memory");
                }
            } else {
                asm volatile("s_waitcnt vmcnt(0)" ::: "memory");
            }
            __builtin_amdgcn_sched_barrier(0);
            __builtin_amdgcn_s_barrier();          // buf[cur] fully landed

            // ---- compute this half: pure LDS + VALU-cvt + MFMA ----
            #pragma unroll
            for (int sl = 0; sl < 4; ++sl) {
                const int sg = h * 4 + sl;
                f16x8 bfr[4];
                #pragma unroll
                for (int rt = 0; rt < 4; ++rt) {
                    const int row = rt * 16 + r16;
                    const int lg0 = sl * 8 + q16 * 2;
                    const float4 lo = *(const float4*)
                        &buf[cur][row * BKH + ((lg0 ^ (row & 7)) << 2)];
                    const float4 hi = *(const float4*)
                        &buf[cur][row * BKH + (((lg0 + 1) ^ (row & 7)) << 2)];
                    f16x8 bb;
                    bb[0] = (f16_t)lo.x; bb[1] = (f16_t)lo.y;
                    bb[2] = (f16_t)lo.z; bb[3] = (f16_t)lo.w;
                    bb[4] = (f16_t)hi.x; bb[5] = (f16_t)hi.y;
                    bb[6] = (f16_t)hi.z; bb[7] = (f16_t)hi.w;
                    bfr[rt] = bb;
                }
                #pragma unroll
                for (int ct = 0; ct < 2; ++ct)
                    #pragma unroll
                    for (int rt = 0; rt < 4; ++rt)
                        acc[ct][rt] = __builtin_amdgcn_mfma_f32_16x16x32_f16(
                            wgall[sg][ct], bfr[rt], acc[ct][rt], 0, 0, 0);
            }
            cur ^= 1;
        }
        first = false;

        // ---- epilogue for tile t (8 stores; tolerated by next tile's vmcnt(12)) ----
        const long gr0 = (long)t * 64;
        if (blockIdx.y == 0) {
            #pragma unroll
            for (int rt = 0; rt < 4; ++rt) {
                const long row = gr0 + rt * 16 + r16;
                const bool ok = row < N_NODES;
                #pragma unroll
                for (int ct = 0; ct < 2; ++ct) {
                    const int colb = w * 32 + ct * 16 + q16 * 4;
                    if (ok) {
                        union { ushort4 u; f16_t hh[4]; } tt;
                        tt.hh[0] = (f16_t)acc[ct][rt][0]; tt.hh[1] = (f16_t)acc[ct][rt][1];
                        tt.hh[2] = (f16_t)acc[ct][rt][2]; tt.hh[3] = (f16_t)acc[ct][rt][3];
                        *(ushort4*)&Pself[row * 256 + colb] = tt.u;
                    }
                }
            }
        } else {
            #pragma unroll
            for (int rt = 0; rt < 4; ++rt) {
                const long row = gr0 + rt * 16 + r16;
                const bool ok = row < N_NODES;
                #pragma unroll
                for (int ct = 0; ct < 2; ++ct) {
                    const int colb = w * 32 + ct * 16 + q16 * 4;
                    unsigned int pk = pk_fp8x4(acc[ct][rt][0], acc[ct][rt][1],
                                               acc[ct][rt][2], acc[ct][rt][3]);
                    if (ok) *(unsigned int*)&Pneigh8[row * 256 + colb] = pk;
                }
            }
        }
        #pragma unroll
        for (int ct = 0; ct < 2; ++ct)
            #pragma unroll
            for (int rt = 0; rt < 4; ++rt) acc[ct][rt] = (f32x4){0.f, 0.f, 0.f, 0.f};
    }
#undef STAGE
}

// ---------------- Kernel 2: out[b] = Pself[ni[b]] + mean_s fp8(Pneigh[nb[b,s]]) ----------------
__global__ __launch_bounds__(256) void gather_add(
    const f16_t* __restrict__ Pself, const unsigned char* __restrict__ P8,
    const int* __restrict__ node_idx, const int* __restrict__ neigh_idx,
    float* __restrict__ out)
{
    const int tid = threadIdx.x, lane = tid & 63, w = tid >> 6;
    const long b0 = (long)blockIdx.x * 8 + w * 2;
    const int c4 = lane * 4;

    int ns0[NSAMP], ns1[NSAMP];
    #pragma unroll
    for (int s = 0; s < NSAMP; ++s) ns0[s] = neigh_idx[b0 * NSAMP + s];
    #pragma unroll
    for (int s = 0; s < NSAMP; ++s) ns1[s] = neigh_idx[(b0 + 1) * NSAMP + s];
    const int sn0 = node_idx[b0], sn1 = node_idx[b0 + 1];

    const ushort4 sv0 = *(const ushort4*)&Pself[(long)sn0 * 256 + c4];
    const ushort4 sv1 = *(const ushort4*)&Pself[(long)sn1 * 256 + c4];

    unsigned int v0[NSAMP], v1[NSAMP];
    #pragma unroll
    for (int s = 0; s < NSAMP; ++s)
        v0[s] = *(const unsigned int*)&P8[(long)ns0[s] * 256 + c4];
    #pragma unroll
    for (int s = 0; s < NSAMP; ++s)
        v1[s] = *(const unsigned int*)&P8[(long)ns1[s] * 256 + c4];

    float4 a0 = make_float4(0.f, 0.f, 0.f, 0.f);
    float4 a1 = make_float4(0.f, 0.f, 0.f, 0.f);
    #pragma unroll
    for (int s = 0; s < NSAMP; ++s) acc_fp8x4(v0[s], a0);
    #pragma unroll
    for (int s = 0; s < NSAMP; ++s) acc_fp8x4(v1[s], a1);

    const float inv = 1.0f / (float)NSAMP;
    float4 o0, o1;
    o0.x = h2f(sv0.x) + a0.x * inv; o0.y = h2f(sv0.y) + a0.y * inv;
    o0.z = h2f(sv0.z) + a0.z * inv; o0.w = h2f(sv0.w) + a0.w * inv;
    o1.x = h2f(sv1.x) + a1.x * inv; o1.y = h2f(sv1.y) + a1.y * inv;
    o1.z = h2f(sv1.z) + a1.z * inv; o1.w = h2f(sv1.w) + a1.w * inv;
    *(float4*)&out[b0 * OUT_F + c4] = o0;
    *(float4*)&out[(b0 + 1) * OUT_F + c4] = o1;
}

// ---------------- Fallback (monolithic) if ws too small ----------------
__device__ __forceinline__ int swz_bf(int row, int us_idx) {
    return us_idx ^ ((row & 7) << 3);
}
__device__ __forceinline__ void store_bf4(unsigned short* comb, int r, int col, float4 f) {
    union { ushort4 u; bf16_t b[4]; } t;
    t.b[0] = (bf16_t)f.x; t.b[1] = (bf16_t)f.y;
    t.b[2] = (bf16_t)f.z; t.b[3] = (bf16_t)f.w;
    *(ushort4*)&comb[swz_bf(r, r * K2 + col)] = t.u;
}
__global__ __launch_bounds__(256, 4) void sage_fused(
    const float* __restrict__ features, const int* __restrict__ node_idx,
    const int* __restrict__ neigh_idx, const float* __restrict__ W,
    float* __restrict__ out)
{
    __shared__ unsigned short comb[16 * K2];
    const int tid = threadIdx.x, lane = tid & 63, wy = tid >> 6;
    const int b0 = blockIdx.x * 16;
    const int col4 = lane * 4;
    #pragma unroll
    for (int i = 0; i < 4; ++i) {
        const int r = wy * 4 + i;
        const long b = b0 + r;
        int nidx[NSAMP];
        #pragma unroll
        for (int s = 0; s < NSAMP; ++s) nidx[s] = neigh_idx[b * NSAMP + s];
        const int self_n = node_idx[b];
        const float4 sf = *(const float4*)&features[(long)self_n * IN_F + col4];
        float4 v[13];
        #pragma unroll
        for (int s = 0; s < 13; ++s)
            v[s] = *(const float4*)&features[(long)nidx[s] * IN_F + col4];
        float4 acc = v[0];
        #pragma unroll
        for (int s = 1; s < 13; ++s) {
            acc.x += v[s].x; acc.y += v[s].y; acc.z += v[s].z; acc.w += v[s].w;
        }
        #pragma unroll
        for (int s = 13; s < NSAMP; ++s)
            v[s - 13] = *(const float4*)&features[(long)nidx[s] * IN_F + col4];
        #pragma unroll
        for (int s = 0; s < 12; ++s) {
            acc.x += v[s].x; acc.y += v[s].y; acc.z += v[s].z; acc.w += v[s].w;
        }
        const float inv = 1.0f / (float)NSAMP;
        acc.x *= inv; acc.y *= inv; acc.z *= inv; acc.w *= inv;
        store_bf4(comb, r, col4, sf);
        store_bf4(comb, r, IN_F + col4, acc);
    }
    __syncthreads();
    const int c0 = wy * 64, arow = lane & 15, kq = (lane >> 4) * 8;
    f32x4 acc[4];
    #pragma unroll
    for (int t = 0; t < 4; ++t) acc[t] = (f32x4){0.f, 0.f, 0.f, 0.f};
    #pragma unroll
    for (int ks = 0; ks < 16; ++ks) {
        const int kb = ks * 32 + kq;
        const bf16x8 af = *(const bf16x8*)&comb[swz_bf(arow, arow * K2 + kb)];
        #pragma unroll
        for (int t = 0; t < 4; ++t) {
            const float* wp = &W[(long)(c0 + t * 16 + arow) * K2 + kb];
            const float4 w0 = *(const float4*)wp;
            const float4 w1 = *(const float4*)(wp + 4);
            bf16x8 bf;
            bf[0] = (bf16_t)w0.x; bf[1] = (bf16_t)w0.y;
            bf[2] = (bf16_t)w0.z; bf[3] = (bf16_t)w0.w;
            bf[4] = (bf16_t)w1.x; bf[5] = (bf16_t)w1.y;
            bf[6] = (bf16_t)w1.z; bf[7] = (bf16_t)w1.w;
            acc[t] = __builtin_amdgcn_mfma_f32_16x16x32_bf16(af, bf, acc[t], 0, 0, 0);
        }
    }
    #pragma unroll
    for (int t = 0; t < 4; ++t) {
        const int col = c0 + t * 16 + arow;
        #pragma unroll
        for (int j = 0; j < 4; ++j) {
            const int row = b0 + (lane >> 4) * 4 + j;
            out[(long)row * OUT_F + col] = acc[t][j];
        }
    }
}

extern "C" void kernel_launch(void* const* d_in, const int* in_sizes, int n_in,
                              void* d_out, int out_size, void* d_ws, size_t ws_size,
                              hipStream_t stream) {
    const float* features  = (const float*)d_in[0];
    const int*   node_idx  = (const int*)d_in[1];
    const int*   neigh_idx = (const int*)d_in[2];
    const float* W         = (const float*)d_in[3];
    float*       out       = (float*)d_out;

    if (ws_size >= (size_t)WS_NEED) {
        f16_t*         Pself  = (f16_t*)d_ws;
        unsigned char* P8     = (unsigned char*)d_ws + P8_OFF;
        f16_t*         Wg     = (f16_t*)((char*)d_ws + WG_OFF);
        wconv<<<512, 256, 0, stream>>>(W, Wg);
        proj_gemm<<<dim3(XS, 2), 512, 0, stream>>>(features, Wg, Pself, P8);
        gather_add<<<BATCH / 8, 256, 0, stream>>>(Pself, P8, node_idx, neigh_idx, out);
    } else {
        sage_fused<<<BATCH / 16, 256, 0, stream>>>(features, node_idx, neigh_idx, W, out);
    }
}

// Round 13
// 125.046 us; speedup vs baseline: 1.3619x; 1.3619x over previous
//
#include <hip/hip_runtime.h>

#define N_NODES 100000
#define IN_F    256
#define OUT_F   256
#define BATCH   50000
#define NSAMP   25
#define K2      512
#define NTILE   1563    // ceil(100000/64)
#define XS      256     // persistent grid x

typedef _Float16 f16_t;
typedef f16_t f16x8 __attribute__((ext_vector_type(8)));
typedef float f32x4 __attribute__((ext_vector_type(4)));
typedef float f32x2 __attribute__((ext_vector_type(2)));
typedef __bf16 bf16_t;
typedef bf16_t bf16x8 __attribute__((ext_vector_type(8)));

#if defined(__has_builtin)
#if __has_builtin(__builtin_amdgcn_cvt_pk_f32_fp8) && __has_builtin(__builtin_amdgcn_cvt_pk_fp8_f32)
#define FP8_HW 1
#endif
#endif
#ifndef FP8_HW
#include <hip/hip_fp8.h>
#endif

// workspace layout (bytes): Pself f16 [100000][256], Pneigh fp8 [100000][256], Wg f16 [512][256]
#define P8_OFF   51200000L
#define WG_OFF   76800000L
#define WS_NEED  (WG_OFF + 512L * 256 * 2)

__device__ __forceinline__ float h2f(unsigned short u) {
    union { unsigned short u; f16_t h; } t; t.u = u; return (float)t.h;
}

__device__ __forceinline__ unsigned int pk_fp8x4(float a, float b, float c, float d) {
#ifdef FP8_HW
    unsigned int r = __builtin_amdgcn_cvt_pk_fp8_f32(a, b, 0u, false);
    r = __builtin_amdgcn_cvt_pk_fp8_f32(c, d, r, true);
    return r;
#else
    union { unsigned char b[4]; unsigned int u; } t;
    t.b[0] = __hip_fp8_e4m3(a).__x; t.b[1] = __hip_fp8_e4m3(b).__x;
    t.b[2] = __hip_fp8_e4m3(c).__x; t.b[3] = __hip_fp8_e4m3(d).__x;
    return t.u;
#endif
}

__device__ __forceinline__ void acc_fp8x4(unsigned int v, float4& a) {
#ifdef FP8_HW
    f32x2 lo = __builtin_amdgcn_cvt_pk_f32_fp8(v, false);
    f32x2 hi = __builtin_amdgcn_cvt_pk_f32_fp8(v, true);
    a.x += lo[0]; a.y += lo[1]; a.z += hi[0]; a.w += hi[1];
#else
    union { unsigned int u; unsigned char b[4]; } t; t.u = v;
    __hip_fp8_e4m3 e0, e1, e2, e3;
    e0.__x = t.b[0]; e1.__x = t.b[1]; e2.__x = t.b[2]; e3.__x = t.b[3];
    a.x += (float)e0; a.y += (float)e1; a.z += (float)e2; a.w += (float)e3;
#endif
}

// ---------------- Kernel 0: rearrange W -> Wg[512][256] f16 ----------------
__global__ void wconv(const float* __restrict__ W, f16_t* __restrict__ Wg) {
    int idx = blockIdx.x * 256 + threadIdx.x;
    int j = idx >> 8, k = idx & 255;
    float v = (j < 256) ? W[j * K2 + k] : W[(j - 256) * K2 + 256 + k];
    Wg[idx] = (f16_t)v;
}

// ---------------- Kernel 1: P = F @ Wg^T (f16 MFMA, f16 LDS staging) ----------------
// grid (256, 2) persistent, 512 threads (8 waves x 32 P-cols).
// y=0 -> Pself (f16), y=1 -> Pneigh (fp8).
// Key change vs R10: the LDS A-tile is f16 (32 KB/tile), not fp32. Each element
// is converted ONCE at stage time (reg-staged: 8 float4 loads/thread issued one
// tile ahead, T14), so the k-loop is pure ds_read_b128 -> MFMA with wgall[8][2]
// (64 VGPR) as the other operand: LDS read traffic halves (256 KB/tile) and the
// per-wave re-conversion (8x amplified cvt) disappears. Waits are compiler-
// counted VGPR dependencies; one __syncthreads per tile (only epilogue stores
// outstanding there — prefetch loads already consumed by the cvt just before).
// Swizzle: 16B granule g of row stored at g ^ (row & 7) -> k-loop reads
// (16 lanes, rows rt*16+r16, same logical granule) spread across all banks.
__global__ __launch_bounds__(512, 2) void proj_gemm(
    const float* __restrict__ features, const f16_t* __restrict__ Wg,
    f16_t* __restrict__ Pself, unsigned char* __restrict__ Pneigh8)
{
    __shared__ unsigned short buf[2][64 * 256];   // 2 x 32 KB f16 (bits)
    const int tid = threadIdx.x, lane = tid & 63, w = tid >> 6;   // w: 0..7
    const int q16 = lane >> 4, r16 = lane & 15;
    const int c0 = blockIdx.y * 256 + w * 32;     // this wave's global P-col base
    const int row_s = tid >> 3;                   // staging row (0..63)
    const int seg_s = tid & 7;                    // staging segment (32 f32 each)

    // ---- hoist the wave's whole Wg slice: 8 k-steps x 2 col-frags = 64 VGPR ----
    f16x8 wgall[8][2];
    #pragma unroll
    for (int s = 0; s < 8; ++s)
        #pragma unroll
        for (int ct = 0; ct < 2; ++ct)
            wgall[s][ct] = *(const f16x8*)&Wg[(long)(c0 + ct * 16 + r16) * 256 + s * 32 + q16 * 8];

    f32x4 acc[2][4];
    #pragma unroll
    for (int ct = 0; ct < 2; ++ct)
        #pragma unroll
        for (int rt = 0; rt < 4; ++rt) acc[ct][rt] = (f32x4){0.f, 0.f, 0.f, 0.f};

    float4 v[8];   // staged fp32 (32 consecutive cols of one row)

#define VLOAD(TT)                                                               \
    {                                                                           \
        long sr_ = (long)(TT) * 64 + row_s;                                     \
        if (sr_ > N_NODES - 1) sr_ = N_NODES - 1;                               \
        const float* p_ = &features[sr_ * IN_F + seg_s * 32];                   \
        _Pragma("unroll")                                                       \
        for (int j_ = 0; j_ < 8; ++j_) v[j_] = *(const float4*)(p_ + j_ * 4);   \
    }

    VLOAD(blockIdx.x);
    int cur = 0;

    for (int t = blockIdx.x; t < NTILE; t += XS) {
        // ---- cvt + swizzled ds_write (consumes v -> compiler waits exactly here) ----
        #pragma unroll
        for (int p = 0; p < 4; ++p) {
            const int g  = seg_s * 4 + p;              // logical 16B granule (0..31)
            const int gp = g ^ (row_s & 7);            // swizzled position
            f16x8 hh;
            hh[0] = (f16_t)v[2 * p].x;     hh[1] = (f16_t)v[2 * p].y;
            hh[2] = (f16_t)v[2 * p].z;     hh[3] = (f16_t)v[2 * p].w;
            hh[4] = (f16_t)v[2 * p + 1].x; hh[5] = (f16_t)v[2 * p + 1].y;
            hh[6] = (f16_t)v[2 * p + 1].z; hh[7] = (f16_t)v[2 * p + 1].w;
            *(f16x8*)&buf[cur][row_s * 256 + gp * 8] = hh;
        }
        __syncthreads();            // drains only epilogue stores; loads already consumed

        if (t + XS < NTILE) VLOAD(t + XS);   // T14: issue next tile's loads now

        // ---- compute: pure ds_read_b128 -> MFMA ----
        #pragma unroll
        for (int sg = 0; sg < 8; ++sg) {
            f16x8 bfr[4];
            #pragma unroll
            for (int rt = 0; rt < 4; ++rt) {
                const int row = rt * 16 + r16;
                const int g   = (sg * 4 + q16) ^ (row & 7);
                bfr[rt] = *(const f16x8*)&buf[cur][row * 256 + g * 8];
            }
            #pragma unroll
            for (int ct = 0; ct < 2; ++ct)
                #pragma unroll
                for (int rt = 0; rt < 4; ++rt)
                    acc[ct][rt] = __builtin_amdgcn_mfma_f32_16x16x32_f16(
                        wgall[sg][ct], bfr[rt], acc[ct][rt], 0, 0, 0);
        }

        // ---- epilogue for tile t ----
        const long gr0 = (long)t * 64;
        if (blockIdx.y == 0) {
            #pragma unroll
            for (int rt = 0; rt < 4; ++rt) {
                const long row = gr0 + rt * 16 + r16;
                const bool ok = row < N_NODES;
                #pragma unroll
                for (int ct = 0; ct < 2; ++ct) {
                    const int colb = w * 32 + ct * 16 + q16 * 4;
                    if (ok) {
                        union { ushort4 u; f16_t hh[4]; } tt;
                        tt.hh[0] = (f16_t)acc[ct][rt][0]; tt.hh[1] = (f16_t)acc[ct][rt][1];
                        tt.hh[2] = (f16_t)acc[ct][rt][2]; tt.hh[3] = (f16_t)acc[ct][rt][3];
                        *(ushort4*)&Pself[row * 256 + colb] = tt.u;
                    }
                }
            }
        } else {
            #pragma unroll
            for (int rt = 0; rt < 4; ++rt) {
                const long row = gr0 + rt * 16 + r16;
                const bool ok = row < N_NODES;
                #pragma unroll
                for (int ct = 0; ct < 2; ++ct) {
                    const int colb = w * 32 + ct * 16 + q16 * 4;
                    unsigned int pk = pk_fp8x4(acc[ct][rt][0], acc[ct][rt][1],
                                               acc[ct][rt][2], acc[ct][rt][3]);
                    if (ok) *(unsigned int*)&Pneigh8[row * 256 + colb] = pk;
                }
            }
        }
        #pragma unroll
        for (int ct = 0; ct < 2; ++ct)
            #pragma unroll
            for (int rt = 0; rt < 4; ++rt) acc[ct][rt] = (f32x4){0.f, 0.f, 0.f, 0.f};
        cur ^= 1;
    }
#undef VLOAD
}

// ---------------- Kernel 2: out[b] = Pself[ni[b]] + mean_s fp8(Pneigh[nb[b,s]]) ----------------
__global__ __launch_bounds__(256) void gather_add(
    const f16_t* __restrict__ Pself, const unsigned char* __restrict__ P8,
    const int* __restrict__ node_idx, const int* __restrict__ neigh_idx,
    float* __restrict__ out)
{
    const int tid = threadIdx.x, lane = tid & 63, w = tid >> 6;
    const long b0 = (long)blockIdx.x * 8 + w * 2;
    const int c4 = lane * 4;

    int ns0[NSAMP], ns1[NSAMP];
    #pragma unroll
    for (int s = 0; s < NSAMP; ++s) ns0[s] = neigh_idx[b0 * NSAMP + s];
    #pragma unroll
    for (int s = 0; s < NSAMP; ++s) ns1[s] = neigh_idx[(b0 + 1) * NSAMP + s];
    const int sn0 = node_idx[b0], sn1 = node_idx[b0 + 1];

    const ushort4 sv0 = *(const ushort4*)&Pself[(long)sn0 * 256 + c4];
    const ushort4 sv1 = *(const ushort4*)&Pself[(long)sn1 * 256 + c4];

    unsigned int v0[NSAMP], v1[NSAMP];
    #pragma unroll
    for (int s = 0; s < NSAMP; ++s)
        v0[s] = *(const unsigned int*)&P8[(long)ns0[s] * 256 + c4];
    #pragma unroll
    for (int s = 0; s < NSAMP; ++s)
        v1[s] = *(const unsigned int*)&P8[(long)ns1[s] * 256 + c4];

    float4 a0 = make_float4(0.f, 0.f, 0.f, 0.f);
    float4 a1 = make_float4(0.f, 0.f, 0.f, 0.f);
    #pragma unroll
    for (int s = 0; s < NSAMP; ++s) acc_fp8x4(v0[s], a0);
    #pragma unroll
    for (int s = 0; s < NSAMP; ++s) acc_fp8x4(v1[s], a1);

    const float inv = 1.0f / (float)NSAMP;
    float4 o0, o1;
    o0.x = h2f(sv0.x) + a0.x * inv; o0.y = h2f(sv0.y) + a0.y * inv;
    o0.z = h2f(sv0.z) + a0.z * inv; o0.w = h2f(sv0.w) + a0.w * inv;
    o1.x = h2f(sv1.x) + a1.x * inv; o1.y = h2f(sv1.y) + a1.y * inv;
    o1.z = h2f(sv1.z) + a1.z * inv; o1.w = h2f(sv1.w) + a1.w * inv;
    *(float4*)&out[b0 * OUT_F + c4] = o0;
    *(float4*)&out[(b0 + 1) * OUT_F + c4] = o1;
}

// ---------------- Fallback (monolithic) if ws too small ----------------
__device__ __forceinline__ int swz_bf(int row, int us_idx) {
    return us_idx ^ ((row & 7) << 3);
}
__device__ __forceinline__ void store_bf4(unsigned short* comb, int r, int col, float4 f) {
    union { ushort4 u; bf16_t b[4]; } t;
    t.b[0] = (bf16_t)f.x; t.b[1] = (bf16_t)f.y;
    t.b[2] = (bf16_t)f.z; t.b[3] = (bf16_t)f.w;
    *(ushort4*)&comb[swz_bf(r, r * K2 + col)] = t.u;
}
__global__ __launch_bounds__(256, 4) void sage_fused(
    const float* __restrict__ features, const int* __restrict__ node_idx,
    const int* __restrict__ neigh_idx, const float* __restrict__ W,
    float* __restrict__ out)
{
    __shared__ unsigned short comb[16 * K2];
    const int tid = threadIdx.x, lane = tid & 63, wy = tid >> 6;
    const int b0 = blockIdx.x * 16;
    const int col4 = lane * 4;
    #pragma unroll
    for (int i = 0; i < 4; ++i) {
        const int r = wy * 4 + i;
        const long b = b0 + r;
        int nidx[NSAMP];
        #pragma unroll
        for (int s = 0; s < NSAMP; ++s) nidx[s] = neigh_idx[b * NSAMP + s];
        const int self_n = node_idx[b];
        const float4 sf = *(const float4*)&features[(long)self_n * IN_F + col4];
        float4 v[13];
        #pragma unroll
        for (int s = 0; s < 13; ++s)
            v[s] = *(const float4*)&features[(long)nidx[s] * IN_F + col4];
        float4 acc = v[0];
        #pragma unroll
        for (int s = 1; s < 13; ++s) {
            acc.x += v[s].x; acc.y += v[s].y; acc.z += v[s].z; acc.w += v[s].w;
        }
        #pragma unroll
        for (int s = 13; s < NSAMP; ++s)
            v[s - 13] = *(const float4*)&features[(long)nidx[s] * IN_F + col4];
        #pragma unroll
        for (int s = 0; s < 12; ++s) {
            acc.x += v[s].x; acc.y += v[s].y; acc.z += v[s].z; acc.w += v[s].w;
        }
        const float inv = 1.0f / (float)NSAMP;
        acc.x *= inv; acc.y *= inv; acc.z *= inv; acc.w *= inv;
        store_bf4(comb, r, col4, sf);
        store_bf4(comb, r, IN_F + col4, acc);
    }
    __syncthreads();
    const int c0 = wy * 64, arow = lane & 15, kq = (lane >> 4) * 8;
    f32x4 acc[4];
    #pragma unroll
    for (int t = 0; t < 4; ++t) acc[t] = (f32x4){0.f, 0.f, 0.f, 0.f};
    #pragma unroll
    for (int ks = 0; ks < 16; ++ks) {
        const int kb = ks * 32 + kq;
        const bf16x8 af = *(const bf16x8*)&comb[swz_bf(arow, arow * K2 + kb)];
        #pragma unroll
        for (int t = 0; t < 4; ++t) {
            const float* wp = &W[(long)(c0 + t * 16 + arow) * K2 + kb];
            const float4 w0 = *(const float4*)wp;
            const float4 w1 = *(const float4*)(wp + 4);
            bf16x8 bf;
            bf[0] = (bf16_t)w0.x; bf[1] = (bf16_t)w0.y;
            bf[2] = (bf16_t)w0.z; bf[3] = (bf16_t)w0.w;
            bf[4] = (bf16_t)w1.x; bf[5] = (bf16_t)w1.y;
            bf[6] = (bf16_t)w1.z; bf[7] = (bf16_t)w1.w;
            acc[t] = __builtin_amdgcn_mfma_f32_16x16x32_bf16(af, bf, acc[t], 0, 0, 0);
        }
    }
    #pragma unroll
    for (int t = 0; t < 4; ++t) {
        const int col = c0 + t * 16 + arow;
        #pragma unroll
        for (int j = 0; j < 4; ++j) {
            const int row = b0 + (lane >> 4) * 4 + j;
            out[(long)row * OUT_F + col] = acc[t][j];
        }
    }
}

extern "C" void kernel_launch(void* const* d_in, const int* in_sizes, int n_in,
                              void* d_out, int out_size, void* d_ws, size_t ws_size,
                              hipStream_t stream) {
    const float* features  = (const float*)d_in[0];
    const int*   node_idx  = (const int*)d_in[1];
    const int*   neigh_idx = (const int*)d_in[2];
    const float* W         = (const float*)d_in[3];
    float*       out       = (float*)d_out;

    if (ws_size >= (size_t)WS_NEED) {
        f16_t*         Pself  = (f16_t*)d_ws;
        unsigned char* P8     = (unsigned char*)d_ws + P8_OFF;
        f16_t*         Wg     = (f16_t*)((char*)d_ws + WG_OFF);
        wconv<<<512, 256, 0, stream>>>(W, Wg);
        proj_gemm<<<dim3(XS, 2), 512, 0, stream>>>(features, Wg, Pself, P8);
        gather_add<<<BATCH / 8, 256, 0, stream>>>(Pself, P8, node_idx, neigh_idx, out);
    } else {
        sage_fused<<<BATCH / 16, 256, 0, stream>>>(features, node_idx, neigh_idx, W, out);
    }
}